// Round 15
// baseline (220.705 us; speedup 1.0000x reference)
//
#include <hip/hip_runtime.h>

#define N_E   4096
#define E_DIM 256
#define NTOK  32768
#define ZX    4096
#define DECAY 0.99f
#define EPSV  1e-5f
#define TAU   0.3f
#define NHB   64        // N_E / 64 code-blocks
#define NSPL  4         // dw splits per code
#define IBIG  0x7fffffff

typedef _Float16 half8 __attribute__((ext_vector_type(8)));
typedef __attribute__((ext_vector_type(4))) float f32x4;

__device__ __forceinline__ unsigned short f2h(float x) {
    _Float16 h = (_Float16)x;
    unsigned short u;
    __builtin_memcpy(&u, &h, 2);
    return u;
}
__device__ __forceinline__ float h2f(unsigned short u) {
    _Float16 h;
    __builtin_memcpy(&h, &u, 2);
    return (float)h;
}
__device__ __forceinline__ unsigned umin2(unsigned a, unsigned b) { return a < b ? a : b; }
__device__ __forceinline__ unsigned umax2(unsigned a, unsigned b) { return a > b ? a : b; }
__device__ __forceinline__ void gload16(const void* g, void* l) {
    __builtin_amdgcn_global_load_lds(
        (const __attribute__((address_space(1))) char*)g,
        (__attribute__((address_space(3))) char*)l, 16, 0, 0);
}

// ---------------- fused prep: blocks <2048 do z->f16; rest do emb prep + init ----------------
__global__ void k_prep(const float* __restrict__ z, unsigned short* __restrict__ zh,
                       const float* __restrict__ emb, unsigned short* __restrict__ Bp,
                       float* __restrict__ enorm32, double* __restrict__ enorm64,
                       int* __restrict__ cnt, int* __restrict__ flagCnt,
                       int* __restrict__ flagCnt2) {
    __shared__ float lt[64][65];
    const int tid = threadIdx.x;
    if (blockIdx.x < 2048) {
        const int bid = blockIdx.x;
        const int xt = bid & 63, ct = (bid >> 6) & 3, b = bid >> 8;
        #pragma unroll
        for (int r = 0; r < 4; ++r) {
            int cy = r * 16 + (tid >> 4);
            int xx4 = tid & 15;
            float4 v = ((const float4*)z)[(size_t)(b * 256 + ct * 64 + cy) * 1024 + xt * 16 + xx4];
            lt[cy][xx4 * 4 + 0] = v.x; lt[cy][xx4 * 4 + 1] = v.y;
            lt[cy][xx4 * 4 + 2] = v.z; lt[cy][xx4 * 4 + 3] = v.w;
        }
        __syncthreads();
        #pragma unroll
        for (int it = 0; it < 2; ++it) {
            int tl = it * 32 + (tid >> 3);
            int c8 = tid & 7;
            unsigned short h[8];
            #pragma unroll
            for (int u = 0; u < 8; ++u) h[u] = f2h(lt[c8 * 8 + u][tl]);
            size_t t = (size_t)(b * 4096 + xt * 64 + tl);
            size_t o = t * 256 + ct * 64 + c8 * 8;
            *(ushort4*)&zh[o]     = make_ushort4(h[0], h[1], h[2], h[3]);
            *(ushort4*)&zh[o + 4] = make_ushort4(h[4], h[5], h[6], h[7]);
        }
    } else {
        const int eb = blockIdx.x - 2048;
        if (tid < 4) cnt[eb * 4 + tid] = 0;
        if (eb == 0 && tid == 0) { *flagCnt = 0; *flagCnt2 = 0; }
        int j = eb * 4 + (tid >> 6);
        int lane = tid & 63;
        float4 v = ((const float4*)emb)[(size_t)j * 64 + lane];
        float f[4] = {v.x, v.y, v.z, v.w};
        unsigned short h[4];
        #pragma unroll
        for (int u = 0; u < 4; ++u) h[u] = f2h(f[u]);
        *(ushort4*)&Bp[(size_t)j * E_DIM + lane * 4] = make_ushort4(h[0], h[1], h[2], h[3]);
        double s = 0.0;
        #pragma unroll
        for (int u = 0; u < 4; ++u) s += (double)f[u] * (double)f[u];
        #pragma unroll
        for (int off = 32; off; off >>= 1) s += __shfl_down(s, off, 64);
        if (lane == 0) { enorm32[j] = (float)s; enorm64[j] = s; }
    }
}

// ---------------- MFMA f16 distance; 128x64 tile (acc[2][4] -> 2x occupancy) ----------------
__global__ __launch_bounds__(256) void k_dist(
        const unsigned short* __restrict__ zh,
        const unsigned short* __restrict__ Bp, const float* __restrict__ enorm32,
        unsigned* __restrict__ pk1, unsigned* __restrict__ pk2, unsigned* __restrict__ pk3) {
    __shared__ __align__(16) char smem[24576];   // 16KB A (128 rows) + 8KB B (64 rows)
    const int tid = threadIdx.x;
    const int lane = tid & 63;
    const int w = tid >> 6;
    // XCD slab swizzle: xcd = n&7 owns tb-slab [xcd*32, xcd*32+32)
    const int n = blockIdx.y * 256 + blockIdx.x;
    const int xcd = n & 7;
    const int mq = n >> 3;
    const int tb = xcd * 32 + (mq & 31);
    const int jb = mq >> 5;                      // 0..63 code-block of 64
    const int t0 = tb * 128;
    const int j0 = jb * 64;
    const int sw16 = (((lane & 7) ^ (lane >> 3)) << 4);
    const int rowsub = lane >> 3;

    f32x4 acc[2][4];
    #pragma unroll
    for (int m = 0; m < 2; ++m)
        #pragma unroll
        for (int nn = 0; nn < 4; ++nn)
            acc[m][nn] = (f32x4){0.f, 0.f, 0.f, 0.f};

    auto stage = [&](int s) {
        const int kb = s * 128 + sw16;
        #pragma unroll
        for (int c = 0; c < 4; ++c) {
            int seg = w * 4 + c;                 // 0..15: A rows
            int arow = t0 + seg * 8 + rowsub;
            gload16((const char*)zh + (size_t)arow * 512 + kb, &smem[seg * 1024]);
        }
        #pragma unroll
        for (int c = 0; c < 2; ++c) {
            int seg = w * 2 + c;                 // 0..7: B rows
            int brow = j0 + seg * 8 + rowsub;
            gload16((const char*)Bp + (size_t)brow * 512 + kb, &smem[16384 + seg * 1024]);
        }
    };

    stage(0);
    for (int s = 0; s < 4; ++s) {
        __syncthreads();                 // staged data visible (vmcnt drained)
        const int xr = ((lane & 7) << 4);
        #pragma unroll
        for (int kk = 0; kk < 2; ++kk) {
            const int colb = (kk * 64 + ((lane >> 4) << 4)) ^ xr;
            half8 a[2], b[4];
            #pragma unroll
            for (int m = 0; m < 2; ++m)
                a[m] = *(const half8*)&smem[((w * 32 + m * 16 + (lane & 15)) << 7) + colb];
            #pragma unroll
            for (int nn = 0; nn < 4; ++nn)
                b[nn] = *(const half8*)&smem[16384 + ((nn * 16 + (lane & 15)) << 7) + colb];
            // swapped operands: D[row=code, col=token]
            #pragma unroll
            for (int m = 0; m < 2; ++m)
                #pragma unroll
                for (int nn = 0; nn < 4; ++nn)
                    acc[m][nn] = __builtin_amdgcn_mfma_f32_16x16x32_f16(b[nn], a[m], acc[m][nn], 0, 0, 0);
        }
        if (s < 3) {
            __syncthreads();             // all waves done reading -> safe to overwrite
            stage(s + 1);
        }
    }

    // ---- epilogue: per-64-code-block top-3 packed u32 keys (6-bit code), 2-pass butterfly ----
    const int g   = lane >> 4;       // code row-group
    const int gg4 = g * 4;
    float enb[4][4];
    #pragma unroll
    for (int nn = 0; nn < 4; ++nn) {
        float4 e4 = *(const float4*)&enorm32[j0 + nn * 16 + gg4];
        enb[nn][0] = e4.x + 4096.f; enb[nn][1] = e4.y + 4096.f;
        enb[nn][2] = e4.z + 4096.f; enb[nn][3] = e4.w + 4096.f;
    }
    unsigned s1 = 0, s2 = 0, s3 = 0;
    #pragma unroll
    for (int m = 0; m < 2; ++m) {
        unsigned k1 = 0xFFFFFFFFu, k2 = 0xFFFFFFFFu, k3 = 0xFFFFFFFFu;
        #pragma unroll
        for (int nn = 0; nn < 4; ++nn)
            #pragma unroll
            for (int r = 0; r < 4; ++r) {
                float sc = fmaf(-2.f, acc[m][nn][r], enb[nn][r]);   // > 0 by construction
                unsigned key = (__float_as_uint(sc) & 0xFFFFFFC0u)
                             | (unsigned)(gg4 + nn * 16 + r);
                k3 = umin2(k3, umax2(k2, key));
                k2 = umin2(k2, umax2(k1, key));
                k1 = umin2(k1, key);
            }
        #pragma unroll
        for (int off = 16; off <= 32; off <<= 1) {
            unsigned b1 = (unsigned)__shfl_xor((int)k1, off, 64);
            unsigned b2 = (unsigned)__shfl_xor((int)k2, off, 64);
            unsigned b3 = (unsigned)__shfl_xor((int)k3, off, 64);
            unsigned p  = umax2(k1, b1);
            unsigned q  = umin2(k2, b2);
            unsigned r2 = umax2(k2, b2);
            unsigned ss = umin2(k3, b3);
            k1 = umin2(k1, b1);
            k2 = umin2(p, q);
            k3 = umin2(umax2(p, q), umin2(r2, ss));
        }
        s1 = (g == m) ? k1 : s1;
        s2 = (g == m) ? k2 : s2;
        s3 = (g == m) ? k3 : s3;
    }
    if (g < 2) {
        size_t o = (size_t)jb * NTOK + t0 + w * 32 + g * 16 + (lane & 15);
        pk1[o] = s1; pk2[o] = s2; pk3[o] = s3;
    }
}

// ---------------- merge code-blocks on keys, histogram, candidate collection ----------------
__global__ void k_merge(const unsigned* __restrict__ pk1, const unsigned* __restrict__ pk2,
                        const unsigned* __restrict__ pk3,
                        int* __restrict__ idx32, int* __restrict__ cnt,
                        float* __restrict__ out_idx,
                        int* __restrict__ xlist, int* __restrict__ xn,
                        int* __restrict__ flagList, int* __restrict__ flagCount,
                        int* __restrict__ flagList2, int* __restrict__ flagCount2) {
    int t = blockIdx.x * blockDim.x + threadIdx.x;
    if (t >= NTOK) return;
    unsigned g1 = 0xFFFFFFFFu, g2 = 0xFFFFFFFFu;
    int h1 = 0;
    #pragma unroll 4
    for (int s = 0; s < NHB; s++) {
        unsigned a = pk1[(size_t)s * NTOK + t];
        unsigned b = pk2[(size_t)s * NTOK + t];
        bool c = a < g1;
        g2 = c ? g1 : umin2(g2, a);
        h1 = c ? s : h1;
        g1 = c ? a : g1;
        g2 = umin2(g2, b);          // b >= a so never the global min
    }
    int x1 = h1 * 64 + (int)(g1 & 63u);
    idx32[t] = x1;
    atomicAdd(&cnt[x1], 1);
    out_idx[t] = (float)x1;
    float v1 = __uint_as_float(g1 & 0xFFFFFFC0u);
    float v2 = __uint_as_float(g2 & 0xFFFFFFC0u);
    if (v2 - v1 >= TAU) return;     // winner certain at fp16 precision
    unsigned thrk = __float_as_uint(v1 + TAU) | 63u;
    int nc = 0; bool full = false;
    for (int s = 0; s < NHB; s++) {
        unsigned a = pk1[(size_t)s * NTOK + t];
        if (a > thrk) continue;
        if (pk3[(size_t)s * NTOK + t] <= thrk) { full = true; break; }  // >=3 in band
        if (nc == 8) { full = true; break; }
        xlist[t * 8 + nc++] = s * 64 + (int)(a & 63u);
        unsigned b = pk2[(size_t)s * NTOK + t];
        if (b <= thrk) {
            if (nc == 8) { full = true; break; }
            xlist[t * 8 + nc++] = s * 64 + (int)(b & 63u);
        }
    }
    if (full) {
        int q = atomicAdd(flagCount2, 1);
        flagList2[q] = t;
    } else {
        xn[t] = nc;
        int q = atomicAdd(flagCount, 1);
        flagList[q] = t;
    }
}

// ---------------- fused referee: blocks<384 tri (candidate lists), rest full recheck ----------------
__global__ __launch_bounds__(512) void k_triR(
        const float* __restrict__ z, const float* __restrict__ emb,
        const double* __restrict__ enorm64,
        const int* __restrict__ flagList, const int* __restrict__ flagCount,
        const int* __restrict__ xlist, const int* __restrict__ xn,
        const int* __restrict__ flagList2, const int* __restrict__ flagCount2,
        int* __restrict__ idx32, int* __restrict__ cnt, float* __restrict__ out_idx) {
    __shared__ float zrow[E_DIM];
    __shared__ double rv[512];
    __shared__ int ri[512];
    const int tid = threadIdx.x;
    if (blockIdx.x < 384) {
        // ---- tri role: exact fp64 over <=8 candidates, one wave per token ----
        const int lane = tid & 63;
        const int wid = blockIdx.x * 8 + (tid >> 6);
        const int nw = 384 * 8;
        const int nf = *flagCount;
        for (int f = wid; f < nf; f += nw) {
            int t = flagList[f];
            int b = t >> 12, x = t & 4095;
            double zz[4];
            #pragma unroll
            for (int u = 0; u < 4; ++u)
                zz[u] = (double)z[(size_t)(b * 256 + lane * 4 + u) * 4096 + x];
            int m = xn[t];
            double best = 1e300; int bi = IBIG;
            for (int c = 0; c < m; ++c) {
                int j = xlist[t * 8 + c];
                float4 e = ((const float4*)emb)[(size_t)j * 64 + lane];
                double d = zz[0] * (double)e.x + zz[1] * (double)e.y
                         + zz[2] * (double)e.z + zz[3] * (double)e.w;
                #pragma unroll
                for (int off = 32; off; off >>= 1) d += __shfl_down(d, off, 64);
                double s = enorm64[j] - 2.0 * d;   // valid on lane 0
                if (s < best || (s == best && j < bi)) { best = s; bi = j; }
            }
            if (lane == 0) {
                int old = idx32[t];
                if (bi != old) {
                    idx32[t] = bi;
                    out_idx[t] = (float)bi;
                    atomicSub(&cnt[old], 1);
                    atomicAdd(&cnt[bi], 1);
                }
            }
        }
    } else {
        // ---- recheck role: full fp64 row scan ----
        const int nf = *flagCount2;
        for (int f = blockIdx.x - 384; f < nf; f += 128) {
            const int t = flagList2[f];
            const int b = t >> 12, x = t & 4095;
            __syncthreads();
            if (tid < E_DIM) zrow[tid] = z[(size_t)(b * 256 + tid) * 4096 + x];
            __syncthreads();
            double best = 1e300; int bi = IBIG;
            for (int s = 0; s < N_E / 512; s++) {
                int j = s * 512 + tid;
                const float4* er4 = (const float4*)(emb + (size_t)j * E_DIM);
                double a0 = 0.0, a1 = 0.0, a2 = 0.0, a3 = 0.0;
                for (int k4 = 0; k4 < 64; ++k4) {
                    float4 e = er4[k4];
                    a0 = fma((double)e.x, (double)zrow[k4 * 4 + 0], a0);
                    a1 = fma((double)e.y, (double)zrow[k4 * 4 + 1], a1);
                    a2 = fma((double)e.z, (double)zrow[k4 * 4 + 2], a2);
                    a3 = fma((double)e.w, (double)zrow[k4 * 4 + 3], a3);
                }
                double d = enorm64[j] - 2.0 * ((a0 + a1) + (a2 + a3));
                if (d < best || (d == best && j < bi)) { best = d; bi = j; }
            }
            rv[tid] = best; ri[tid] = bi;
            __syncthreads();
            for (int off = 256; off; off >>= 1) {
                if (tid < off) {
                    if (rv[tid + off] < rv[tid] ||
                        (rv[tid + off] == rv[tid] && ri[tid + off] < ri[tid])) {
                        rv[tid] = rv[tid + off]; ri[tid] = ri[tid + off];
                    }
                }
                __syncthreads();
            }
            if (tid == 0) {
                int old = idx32[t];
                int nw2 = ri[0];
                if (nw2 != old) {
                    idx32[t] = nw2;
                    out_idx[t] = (float)nw2;
                    atomicSub(&cnt[old], 1);
                    atomicAdd(&cnt[nw2], 1);
                }
            }
            __syncthreads();
        }
    }
}

// ---------------- exclusive scan of cnt[4096] + n/usage stats ----------------
__global__ void k_scan(const int* __restrict__ cnt, int* __restrict__ offs,
                       const float* __restrict__ cluster_size,
                       float* __restrict__ nval, float* __restrict__ out_usage) {
    __shared__ int sc[1024];
    __shared__ float sn[1024];
    __shared__ float su[1024];
    int tid = threadIdx.x;
    int c0 = cnt[tid * 4], c1 = cnt[tid * 4 + 1], c2 = cnt[tid * 4 + 2], c3 = cnt[tid * 4 + 3];
    int ls = c0 + c1 + c2 + c3;
    float ns = 0.f, us = 0.f;
    {
        int cc[4] = {c0, c1, c2, c3};
        #pragma unroll
        for (int u = 0; u < 4; ++u) {
            ns += cluster_size[tid * 4 + u] * DECAY + (1.f - DECAY) * (float)cc[u];
            us += (cc[u] > 0) ? 1.f : 0.f;
        }
    }
    sc[tid] = ls; sn[tid] = ns; su[tid] = us;
    __syncthreads();
    for (int off = 1; off < 1024; off <<= 1) {
        int v = (tid >= off) ? sc[tid - off] : 0;
        __syncthreads();
        sc[tid] += v;
        __syncthreads();
    }
    int base = sc[tid] - ls;
    offs[tid * 4] = base;
    offs[tid * 4 + 1] = base + c0;
    offs[tid * 4 + 2] = base + c0 + c1;
    offs[tid * 4 + 3] = base + c0 + c1 + c2;
    for (int off = 512; off; off >>= 1) {
        if (tid < off) { sn[tid] += sn[tid + off]; su[tid] += su[tid + off]; }
        __syncthreads();
    }
    if (tid == 0) { *nval = sn[0]; *out_usage = su[0] / (float)N_E; }
}

// ---------------- place tokens into per-code lists ----------------
__global__ void k_place(const int* __restrict__ idx32, int* __restrict__ offs,
                        int* __restrict__ tokList) {
    int t = blockIdx.x * blockDim.x + threadIdx.x;
    if (t >= NTOK) return;
    int j = idx32[t];
    int p = atomicAdd(&offs[j], 1);
    tokList[p] = t;
}

// ---------------- fused: dw partials (latency-bound) || zq gather (write-BW-bound) ----------------
__global__ __launch_bounds__(512) void k_dwzq(const unsigned short* __restrict__ zh,
                       const int* __restrict__ cnt, const int* __restrict__ offs,
                       const int* __restrict__ tokList, float* __restrict__ dwp,
                       const float* __restrict__ emb, const int* __restrict__ idx32,
                       float* __restrict__ out_zq) {
    __shared__ float red[8][256];
    if (blockIdx.x < N_E) {
        const int j = blockIdx.x;
        const int split = blockIdx.y;          // 0..NSPL-1
        const int g = threadIdx.x >> 6;        // 0..7
        const int lane = threadIdx.x & 63;
        const int n = cnt[j];
        const int s0 = offs[j] - n;            // offs holds end positions after k_place
        const int stride = NSPL * 8;           // 32
        float4 acc = make_float4(0.f, 0.f, 0.f, 0.f);
        int i = split * 8 + g;
        if (i < n) {
            int t_cur = tokList[s0 + i];
            i += stride;
            for (; i < n; i += stride) {
                int t_nxt = tokList[s0 + i];   // overlaps with zh gather below
                ushort4 h = *(const ushort4*)&zh[(size_t)t_cur * 256 + lane * 4];
                acc.x += h2f(h.x); acc.y += h2f(h.y);
                acc.z += h2f(h.z); acc.w += h2f(h.w);
                t_cur = t_nxt;
            }
            ushort4 h = *(const ushort4*)&zh[(size_t)t_cur * 256 + lane * 4];
            acc.x += h2f(h.x); acc.y += h2f(h.y);
            acc.z += h2f(h.z); acc.w += h2f(h.w);
        }
        red[g][lane * 4 + 0] = acc.x; red[g][lane * 4 + 1] = acc.y;
        red[g][lane * 4 + 2] = acc.z; red[g][lane * 4 + 3] = acc.w;
        __syncthreads();
        if (g == 0) {
            float4 o;
            int c = lane * 4;
            o.x = red[0][c+0] + red[1][c+0] + red[2][c+0] + red[3][c+0]
                + red[4][c+0] + red[5][c+0] + red[6][c+0] + red[7][c+0];
            o.y = red[0][c+1] + red[1][c+1] + red[2][c+1] + red[3][c+1]
                + red[4][c+1] + red[5][c+1] + red[6][c+1] + red[7][c+1];
            o.z = red[0][c+2] + red[1][c+2] + red[2][c+2] + red[3][c+2]
                + red[4][c+2] + red[5][c+2] + red[6][c+2] + red[7][c+2];
            o.w = red[0][c+3] + red[1][c+3] + red[2][c+3] + red[3][c+3]
                + red[4][c+3] + red[5][c+3] + red[6][c+3] + red[7][c+3];
            ((float4*)dwp)[((size_t)split * N_E + j) * 64 + lane] = o;
        }
    } else {
        // zq role: 512 tokens per block, thread-per-token, 256B-contiguous wave stores
        int t = (blockIdx.x - N_E) * (NSPL * 512) + blockIdx.y * 512 + threadIdx.x;
        int j = idx32[t];
        int b = t >> 12, x = t & 4095;
        const float4* er = (const float4*)(emb + (size_t)j * E_DIM);
        float* ob = out_zq + (size_t)b * (E_DIM * ZX) + x;
        #pragma unroll 8
        for (int c4 = 0; c4 < E_DIM / 4; c4++) {
            float4 v = er[c4];
            ob[(size_t)(c4 * 4 + 0) * ZX] = v.x;
            ob[(size_t)(c4 * 4 + 1) * ZX] = v.y;
            ob[(size_t)(c4 * 4 + 2) * ZX] = v.z;
            ob[(size_t)(c4 * 4 + 3) * ZX] = v.w;
        }
    }
}

// ---------------- final: sum split partials + EMA epilogue ----------------
__global__ void k_final(const float* __restrict__ dwp, const int* __restrict__ cnt,
                        const float* __restrict__ cluster_size,
                        const float* __restrict__ emb_avg, const float* __restrict__ nval,
                        float* __restrict__ out_cluster, float* __restrict__ out_avg,
                        float* __restrict__ out_embed) {
    int j = blockIdx.x * 4 + (threadIdx.x >> 6);
    int lane = threadIdx.x & 63;
    float4 dw = make_float4(0.f, 0.f, 0.f, 0.f);
    #pragma unroll
    for (int s = 0; s < NSPL; ++s) {
        float4 v = ((const float4*)dwp)[((size_t)s * N_E + j) * 64 + lane];
        dw.x += v.x; dw.y += v.y; dw.z += v.z; dw.w += v.w;
    }
    float nc = cluster_size[j] * DECAY + (1.f - DECAY) * (float)cnt[j];
    float nv = *nval;
    float cs = (nc + EPSV) / (nv + (float)N_E * EPSV) * nv;
    float4 ea = ((const float4*)emb_avg)[(size_t)j * 64 + lane];
    float4 na, ne;
    na.x = ea.x * DECAY + (1.f - DECAY) * dw.x;
    na.y = ea.y * DECAY + (1.f - DECAY) * dw.y;
    na.z = ea.z * DECAY + (1.f - DECAY) * dw.z;
    na.w = ea.w * DECAY + (1.f - DECAY) * dw.w;
    ne.x = na.x / cs; ne.y = na.y / cs; ne.z = na.z / cs; ne.w = na.w / cs;
    ((float4*)out_avg)[(size_t)j * 64 + lane] = na;
    ((float4*)out_embed)[(size_t)j * 64 + lane] = ne;
    if (lane == 0) out_cluster[j] = nc;
}

extern "C" void kernel_launch(void* const* d_in, const int* in_sizes, int n_in,
                              void* d_out, int out_size, void* d_ws, size_t ws_size,
                              hipStream_t stream) {
    const float* z            = (const float*)d_in[0];
    const float* emb          = (const float*)d_in[1];
    const float* cluster_size = (const float*)d_in[2];
    const float* emb_avg      = (const float*)d_in[3];
    float* out = (float*)d_out;

    // ---- d_ws layout (bytes), ~35.8 MB (R1 used 39.6 MB safely) ----
    char* ws = (char*)d_ws;
    unsigned short* zh   = (unsigned short*)(ws + 0);          // 16,777,216 (f16)
    float* enorm32       = (float*)(ws + 16777216);            // 16,384
    double* enorm64      = (double*)(ws + 16793600);           // 32,768
    int* idx32           = (int*)(ws + 16826368);              // 131,072
    int* flagList        = (int*)(ws + 16957440);              // 131,072
    int* flagList2       = (int*)(ws + 17088512);              // 131,072
    int* xlist           = (int*)(ws + 17219584);              // 1,048,576
    int* xn              = (int*)(ws + 18268160);              // 131,072
    int* cnt             = (int*)(ws + 18399232);              // 16,384
    int* offs            = (int*)(ws + 18415616);              // 16,384
    int* flagCnt         = (int*)(ws + 18432000);              // 64
    int* flagCnt2        = (int*)(ws + 18432064);              // 64
    float* nval          = (float*)(ws + 18432128);            // 64
    float* dwp           = (float*)(ws + 18874368);            // 16,777,216 (NSPL partials)
    int*   tokList       = (int*)(ws + 35651584);              // 131,072 (ends 35,782,656)

    // ---- scratch inside d_out's zq region (pk/Bp dead before zq written) ----
    unsigned* pk1        = (unsigned*)(out + 0);        // 8 MB (64 x NTOK)
    unsigned* pk2        = (unsigned*)(out + 2097152);  // 8 MB
    unsigned* pk3        = (unsigned*)(out + 4194304);  // 8 MB
    unsigned short* Bp   = (unsigned short*)(out + 6291456);   // 2 MB (ends byte 27,262,976)

    // ---- output sections ----
    float* out_zq      = out + 0;
    float* out_idx     = out + 8388608;
    float* out_cluster = out + 8421376;
    float* out_avg     = out + 8425472;
    float* out_embed   = out + 9474048;
    float* out_usage   = out + 10522624;

    hipLaunchKernelGGL(k_prep,   dim3(3072), dim3(256), 0, stream,
                       z, zh, emb, Bp, enorm32, enorm64, cnt, flagCnt, flagCnt2);
    hipLaunchKernelGGL(k_dist,   dim3(256, NHB), dim3(256), 0, stream,
                       zh, Bp, enorm32, pk1, pk2, pk3);
    hipLaunchKernelGGL(k_merge,  dim3(128), dim3(256), 0, stream,
                       pk1, pk2, pk3, idx32, cnt, out_idx,
                       xlist, xn, flagList, flagCnt, flagList2, flagCnt2);
    hipLaunchKernelGGL(k_triR,   dim3(512), dim3(512), 0, stream,
                       z, emb, enorm64, flagList, flagCnt, xlist, xn,
                       flagList2, flagCnt2, idx32, cnt, out_idx);
    hipLaunchKernelGGL(k_scan,   dim3(1), dim3(1024), 0, stream, cnt, offs,
                       cluster_size, nval, out_usage);
    hipLaunchKernelGGL(k_place,  dim3(128), dim3(256), 0, stream, idx32, offs, tokList);
    hipLaunchKernelGGL(k_dwzq,   dim3(N_E + 16, NSPL), dim3(512), 0, stream,
                       zh, cnt, offs, tokList, dwp, emb, idx32, out_zq);
    hipLaunchKernelGGL(k_final,  dim3(1024), dim3(256), 0, stream,
                       dwp, cnt, cluster_size, emb_avg, nval,
                       out_cluster, out_avg, out_embed);
}

// Round 17
// 200.831 us; speedup vs baseline: 1.0990x; 1.0990x over previous
//
#include <hip/hip_runtime.h>

#define N_E   4096
#define E_DIM 256
#define NTOK  32768
#define ZX    4096
#define DECAY 0.99f
#define EPSV  1e-5f
#define TAU   0.3f
#define NJB   32        // N_E / 128 j-blocks
#define NSPL  4         // dw splits per code
#define IBIG  0x7fffffff

typedef _Float16 half8 __attribute__((ext_vector_type(8)));
typedef __attribute__((ext_vector_type(4))) float f32x4;

__device__ __forceinline__ unsigned short f2h(float x) {
    _Float16 h = (_Float16)x;
    unsigned short u;
    __builtin_memcpy(&u, &h, 2);
    return u;
}
__device__ __forceinline__ float h2f(unsigned short u) {
    _Float16 h;
    __builtin_memcpy(&h, &u, 2);
    return (float)h;
}
__device__ __forceinline__ unsigned umin2(unsigned a, unsigned b) { return a < b ? a : b; }
__device__ __forceinline__ unsigned umax2(unsigned a, unsigned b) { return a > b ? a : b; }
__device__ __forceinline__ void gload16(const void* g, void* l) {
    __builtin_amdgcn_global_load_lds(
        (const __attribute__((address_space(1))) char*)g,
        (__attribute__((address_space(3))) char*)l, 16, 0, 0);
}

// ---------------- fused prep: blocks <2048 do z->f16; rest do emb prep + init ----------------
__global__ void k_prep(const float* __restrict__ z, unsigned short* __restrict__ zh,
                       const float* __restrict__ emb, unsigned short* __restrict__ Bp,
                       float* __restrict__ enorm32, double* __restrict__ enorm64,
                       int* __restrict__ cnt, int* __restrict__ flagCnt,
                       int* __restrict__ flagCnt2) {
    __shared__ float lt[64][65];
    const int tid = threadIdx.x;
    if (blockIdx.x < 2048) {
        const int bid = blockIdx.x;
        const int xt = bid & 63, ct = (bid >> 6) & 3, b = bid >> 8;
        #pragma unroll
        for (int r = 0; r < 4; ++r) {
            int cy = r * 16 + (tid >> 4);
            int xx4 = tid & 15;
            float4 v = ((const float4*)z)[(size_t)(b * 256 + ct * 64 + cy) * 1024 + xt * 16 + xx4];
            lt[cy][xx4 * 4 + 0] = v.x; lt[cy][xx4 * 4 + 1] = v.y;
            lt[cy][xx4 * 4 + 2] = v.z; lt[cy][xx4 * 4 + 3] = v.w;
        }
        __syncthreads();
        #pragma unroll
        for (int it = 0; it < 2; ++it) {
            int tl = it * 32 + (tid >> 3);
            int c8 = tid & 7;
            unsigned short h[8];
            #pragma unroll
            for (int u = 0; u < 8; ++u) h[u] = f2h(lt[c8 * 8 + u][tl]);
            size_t t = (size_t)(b * 4096 + xt * 64 + tl);
            size_t o = t * 256 + ct * 64 + c8 * 8;
            *(ushort4*)&zh[o]     = make_ushort4(h[0], h[1], h[2], h[3]);
            *(ushort4*)&zh[o + 4] = make_ushort4(h[4], h[5], h[6], h[7]);
        }
    } else {
        const int eb = blockIdx.x - 2048;
        if (tid < 4) cnt[eb * 4 + tid] = 0;
        if (eb == 0 && tid == 0) { *flagCnt = 0; *flagCnt2 = 0; }
        int j = eb * 4 + (tid >> 6);
        int lane = tid & 63;
        float4 v = ((const float4*)emb)[(size_t)j * 64 + lane];
        float f[4] = {v.x, v.y, v.z, v.w};
        unsigned short h[4];
        #pragma unroll
        for (int u = 0; u < 4; ++u) h[u] = f2h(f[u]);
        *(ushort4*)&Bp[(size_t)j * E_DIM + lane * 4] = make_ushort4(h[0], h[1], h[2], h[3]);
        double s = 0.0;
        #pragma unroll
        for (int u = 0; u < 4; ++u) s += (double)f[u] * (double)f[u];
        #pragma unroll
        for (int off = 32; off; off >>= 1) s += __shfl_down(s, off, 64);
        if (lane == 0) { enorm32[j] = (float)s; enorm64[j] = s; }
    }
}

// ---------------- MFMA f16 distance; XCD-slab swizzle; per-jb top-3 packed keys ----------------
__global__ __launch_bounds__(256) void k_dist(
        const unsigned short* __restrict__ zh,
        const unsigned short* __restrict__ Bp, const float* __restrict__ enorm32,
        unsigned* __restrict__ pk1, unsigned* __restrict__ pk2, unsigned* __restrict__ pk3) {
    __shared__ __align__(16) char smem[32768];   // single buffer: 16KB A + 16KB B
    const int tid = threadIdx.x;
    const int lane = tid & 63;
    const int w = tid >> 6;
    const int wr = w >> 1, wc = w & 1;
    // XCD slab swizzle: xcd = n&7 owns tb-slab [xcd*32, xcd*32+32)
    const int n = blockIdx.y * 256 + blockIdx.x;
    const int xcd = n & 7;
    const int mq = n >> 3;
    const int tb = xcd * 32 + (mq & 31);
    const int jb = mq >> 5;
    const int t0 = tb * 128;
    const int j0 = jb * 128;
    const int sw16 = (((lane & 7) ^ (lane >> 3)) << 4);
    const int rowsub = lane >> 3;

    f32x4 acc[4][4];
    #pragma unroll
    for (int m = 0; m < 4; ++m)
        #pragma unroll
        for (int nn = 0; nn < 4; ++nn)
            acc[m][nn] = (f32x4){0.f, 0.f, 0.f, 0.f};

    auto stage = [&](int s) {
        const int kb = s * 128 + sw16;
        #pragma unroll
        for (int c = 0; c < 4; ++c) {
            int seg = w * 4 + c;
            int arow = t0 + seg * 8 + rowsub;
            int brow = j0 + seg * 8 + rowsub;
            gload16((const char*)zh + (size_t)arow * 512 + kb, &smem[seg * 1024]);
            gload16((const char*)Bp + (size_t)brow * 512 + kb, &smem[16384 + seg * 1024]);
        }
    };

    stage(0);
    for (int s = 0; s < 4; ++s) {
        __syncthreads();                 // staged data visible (vmcnt drained)
        const int xr = ((lane & 7) << 4);
        #pragma unroll
        for (int kk = 0; kk < 2; ++kk) {
            const int colb = (kk * 64 + ((lane >> 4) << 4)) ^ xr;
            half8 a[4], b[4];
            #pragma unroll
            for (int m = 0; m < 4; ++m)
                a[m] = *(const half8*)&smem[((wr * 64 + m * 16 + (lane & 15)) << 7) + colb];
            #pragma unroll
            for (int nn = 0; nn < 4; ++nn)
                b[nn] = *(const half8*)&smem[16384 + ((wc * 64 + nn * 16 + (lane & 15)) << 7) + colb];
            // swapped operands: D[row=code, col=token]
            #pragma unroll
            for (int m = 0; m < 4; ++m)
                #pragma unroll
                for (int nn = 0; nn < 4; ++nn)
                    acc[m][nn] = __builtin_amdgcn_mfma_f32_16x16x32_f16(b[nn], a[m], acc[m][nn], 0, 0, 0);
        }
        if (s < 3) {
            __syncthreads();             // all waves done reading -> safe to overwrite
            stage(s + 1);
        }
    }

    // ---- epilogue: per-(wc)half top-3 packed u32 keys (7-bit code), 2-pass butterfly ----
    const int g   = lane >> 4;       // code row-group
    const int gg4 = g * 4;
    const int cbase = (wc << 6);
    float enb[4][4];
    #pragma unroll
    for (int nn = 0; nn < 4; ++nn) {
        float4 e4 = *(const float4*)&enorm32[j0 + wc * 64 + nn * 16 + gg4];
        enb[nn][0] = e4.x + 4096.f; enb[nn][1] = e4.y + 4096.f;
        enb[nn][2] = e4.z + 4096.f; enb[nn][3] = e4.w + 4096.f;
    }
    unsigned s1 = 0, s2 = 0, s3 = 0;
    #pragma unroll
    for (int m = 0; m < 4; ++m) {
        unsigned k1 = 0xFFFFFFFFu, k2 = 0xFFFFFFFFu, k3 = 0xFFFFFFFFu;
        #pragma unroll
        for (int nn = 0; nn < 4; ++nn)
            #pragma unroll
            for (int r = 0; r < 4; ++r) {
                float sc = fmaf(-2.f, acc[m][nn][r], enb[nn][r]);   // > 0 by construction
                unsigned key = (__float_as_uint(sc) & 0xFFFFFF80u)
                             | (unsigned)(cbase | (gg4 + nn * 16 + r));
                k3 = umin2(k3, umax2(k2, key));
                k2 = umin2(k2, umax2(k1, key));
                k1 = umin2(k1, key);
            }
        #pragma unroll
        for (int off = 16; off <= 32; off <<= 1) {
            unsigned b1 = (unsigned)__shfl_xor((int)k1, off, 64);
            unsigned b2 = (unsigned)__shfl_xor((int)k2, off, 64);
            unsigned b3 = (unsigned)__shfl_xor((int)k3, off, 64);
            unsigned p  = umax2(k1, b1);
            unsigned q  = umin2(k2, b2);
            unsigned r2 = umax2(k2, b2);
            unsigned ss = umin2(k3, b3);
            k1 = umin2(k1, b1);
            k2 = umin2(p, q);
            k3 = umin2(umax2(p, q), umin2(r2, ss));
        }
        s1 = (g == m) ? k1 : s1;
        s2 = (g == m) ? k2 : s2;
        s3 = (g == m) ? k3 : s3;
    }
    // ---- cross-wc merge via LDS (tiles dead after barrier) -> per-128-code top-3 ----
    unsigned* mb = (unsigned*)smem;      // [3][2][64]
    __syncthreads();                     // all GEMM LDS reads complete
    if (wc == 1) {
        mb[wr * 64 + lane]       = s1;
        mb[128 + wr * 64 + lane] = s2;
        mb[256 + wr * 64 + lane] = s3;
    }
    __syncthreads();
    if (wc == 0) {
        unsigned o1 = mb[wr * 64 + lane];
        unsigned o2 = mb[128 + wr * 64 + lane];
        unsigned o3 = mb[256 + wr * 64 + lane];
        unsigned r1 = umin2(s1, o1);
        unsigned A  = umax2(s1, o1);
        unsigned B  = umin2(s2, o2);
        unsigned C  = umax2(s2, o2);
        unsigned D  = umin2(s3, o3);
        unsigned r2 = umin2(A, B);
        unsigned r3 = umin2(umax2(A, B), umin2(C, D));
        size_t o = (size_t)jb * NTOK + t0 + wr * 64 + lane;
        pk1[o] = r1; pk2[o] = r2; pk3[o] = r3;
    }
}

// ---------------- merge jb-blocks on keys, histogram, candidate collection ----------------
__global__ void k_merge(const unsigned* __restrict__ pk1, const unsigned* __restrict__ pk2,
                        const unsigned* __restrict__ pk3,
                        int* __restrict__ idx32, int* __restrict__ cnt,
                        float* __restrict__ out_idx,
                        int* __restrict__ xlist, int* __restrict__ xn,
                        int* __restrict__ flagList, int* __restrict__ flagCount,
                        int* __restrict__ flagList2, int* __restrict__ flagCount2) {
    int t = blockIdx.x * blockDim.x + threadIdx.x;
    if (t >= NTOK) return;
    unsigned g1 = 0xFFFFFFFFu, g2 = 0xFFFFFFFFu;
    int h1 = 0;
    #pragma unroll 4
    for (int s = 0; s < NJB; s++) {
        unsigned a = pk1[(size_t)s * NTOK + t];
        unsigned b = pk2[(size_t)s * NTOK + t];
        bool c = a < g1;
        g2 = c ? g1 : umin2(g2, a);
        h1 = c ? s : h1;
        g1 = c ? a : g1;
        g2 = umin2(g2, b);          // b >= a so never the global min
    }
    int x1 = h1 * 128 + (int)(g1 & 127u);
    idx32[t] = x1;
    atomicAdd(&cnt[x1], 1);
    out_idx[t] = (float)x1;
    float v1 = __uint_as_float(g1 & 0xFFFFFF80u);
    float v2 = __uint_as_float(g2 & 0xFFFFFF80u);
    if (v2 - v1 >= TAU) return;     // winner certain at fp16 precision
    unsigned thrk = __float_as_uint(v1 + TAU) | 127u;
    int nc = 0; bool full = false;
    for (int s = 0; s < NJB; s++) {
        unsigned a = pk1[(size_t)s * NTOK + t];
        if (a > thrk) continue;
        if (pk3[(size_t)s * NTOK + t] <= thrk) { full = true; break; }  // >=3 in band
        if (nc == 8) { full = true; break; }
        xlist[t * 8 + nc++] = s * 128 + (int)(a & 127u);
        unsigned b = pk2[(size_t)s * NTOK + t];
        if (b <= thrk) {
            if (nc == 8) { full = true; break; }
            xlist[t * 8 + nc++] = s * 128 + (int)(b & 127u);
        }
    }
    if (full) {
        int q = atomicAdd(flagCount2, 1);
        flagList2[q] = t;
    } else {
        xn[t] = nc;
        int q = atomicAdd(flagCount, 1);
        flagList[q] = t;
    }
}

// ---------------- fused referee: blocks<384 tri (candidate lists), rest full recheck ----------------
__global__ __launch_bounds__(512) void k_triR(
        const float* __restrict__ z, const float* __restrict__ emb,
        const double* __restrict__ enorm64,
        const int* __restrict__ flagList, const int* __restrict__ flagCount,
        const int* __restrict__ xlist, const int* __restrict__ xn,
        const int* __restrict__ flagList2, const int* __restrict__ flagCount2,
        int* __restrict__ idx32, int* __restrict__ cnt, float* __restrict__ out_idx) {
    __shared__ float zrow[E_DIM];
    __shared__ double rv[512];
    __shared__ int ri[512];
    const int tid = threadIdx.x;
    if (blockIdx.x < 384) {
        // ---- tri role: exact fp64 over <=8 candidates, one wave per token ----
        const int lane = tid & 63;
        const int wid = blockIdx.x * 8 + (tid >> 6);
        const int nw = 384 * 8;
        const int nf = *flagCount;
        for (int f = wid; f < nf; f += nw) {
            int t = flagList[f];
            int b = t >> 12, x = t & 4095;
            double zz[4];
            #pragma unroll
            for (int u = 0; u < 4; ++u)
                zz[u] = (double)z[(size_t)(b * 256 + lane * 4 + u) * 4096 + x];
            int m = xn[t];
            double best = 1e300; int bi = IBIG;
            for (int c = 0; c < m; ++c) {
                int j = xlist[t * 8 + c];
                float4 e = ((const float4*)emb)[(size_t)j * 64 + lane];
                double d = zz[0] * (double)e.x + zz[1] * (double)e.y
                         + zz[2] * (double)e.z + zz[3] * (double)e.w;
                #pragma unroll
                for (int off = 32; off; off >>= 1) d += __shfl_down(d, off, 64);
                double s = enorm64[j] - 2.0 * d;   // valid on lane 0
                if (s < best || (s == best && j < bi)) { best = s; bi = j; }
            }
            if (lane == 0) {
                int old = idx32[t];
                if (bi != old) {
                    idx32[t] = bi;
                    out_idx[t] = (float)bi;
                    atomicSub(&cnt[old], 1);
                    atomicAdd(&cnt[bi], 1);
                }
            }
        }
    } else {
        // ---- recheck role: full fp64 row scan ----
        const int nf = *flagCount2;
        for (int f = blockIdx.x - 384; f < nf; f += 128) {
            const int t = flagList2[f];
            const int b = t >> 12, x = t & 4095;
            __syncthreads();
            if (tid < E_DIM) zrow[tid] = z[(size_t)(b * 256 + tid) * 4096 + x];
            __syncthreads();
            double best = 1e300; int bi = IBIG;
            for (int s = 0; s < N_E / 512; s++) {
                int j = s * 512 + tid;
                const float4* er4 = (const float4*)(emb + (size_t)j * E_DIM);
                double a0 = 0.0, a1 = 0.0, a2 = 0.0, a3 = 0.0;
                for (int k4 = 0; k4 < 64; ++k4) {
                    float4 e = er4[k4];
                    a0 = fma((double)e.x, (double)zrow[k4 * 4 + 0], a0);
                    a1 = fma((double)e.y, (double)zrow[k4 * 4 + 1], a1);
                    a2 = fma((double)e.z, (double)zrow[k4 * 4 + 2], a2);
                    a3 = fma((double)e.w, (double)zrow[k4 * 4 + 3], a3);
                }
                double d = enorm64[j] - 2.0 * ((a0 + a1) + (a2 + a3));
                if (d < best || (d == best && j < bi)) { best = d; bi = j; }
            }
            rv[tid] = best; ri[tid] = bi;
            __syncthreads();
            for (int off = 256; off; off >>= 1) {
                if (tid < off) {
                    if (rv[tid + off] < rv[tid] ||
                        (rv[tid + off] == rv[tid] && ri[tid + off] < ri[tid])) {
                        rv[tid] = rv[tid + off]; ri[tid] = ri[tid + off];
                    }
                }
                __syncthreads();
            }
            if (tid == 0) {
                int old = idx32[t];
                int nw2 = ri[0];
                if (nw2 != old) {
                    idx32[t] = nw2;
                    out_idx[t] = (float)nw2;
                    atomicSub(&cnt[old], 1);
                    atomicAdd(&cnt[nw2], 1);
                }
            }
            __syncthreads();
        }
    }
}

// ---------------- exclusive scan of cnt[4096] + n/usage stats ----------------
__global__ void k_scan(const int* __restrict__ cnt, int* __restrict__ offs,
                       const float* __restrict__ cluster_size,
                       float* __restrict__ nval, float* __restrict__ out_usage) {
    __shared__ int sc[1024];
    __shared__ float sn[1024];
    __shared__ float su[1024];
    int tid = threadIdx.x;
    int c0 = cnt[tid * 4], c1 = cnt[tid * 4 + 1], c2 = cnt[tid * 4 + 2], c3 = cnt[tid * 4 + 3];
    int ls = c0 + c1 + c2 + c3;
    float ns = 0.f, us = 0.f;
    {
        int cc[4] = {c0, c1, c2, c3};
        #pragma unroll
        for (int u = 0; u < 4; ++u) {
            ns += cluster_size[tid * 4 + u] * DECAY + (1.f - DECAY) * (float)cc[u];
            us += (cc[u] > 0) ? 1.f : 0.f;
        }
    }
    sc[tid] = ls; sn[tid] = ns; su[tid] = us;
    __syncthreads();
    for (int off = 1; off < 1024; off <<= 1) {
        int v = (tid >= off) ? sc[tid - off] : 0;
        __syncthreads();
        sc[tid] += v;
        __syncthreads();
    }
    int base = sc[tid] - ls;
    offs[tid * 4] = base;
    offs[tid * 4 + 1] = base + c0;
    offs[tid * 4 + 2] = base + c0 + c1;
    offs[tid * 4 + 3] = base + c0 + c1 + c2;
    for (int off = 512; off; off >>= 1) {
        if (tid < off) { sn[tid] += sn[tid + off]; su[tid] += su[tid + off]; }
        __syncthreads();
    }
    if (tid == 0) { *nval = sn[0]; *out_usage = su[0] / (float)N_E; }
}

// ---------------- place tokens into per-code lists ----------------
__global__ void k_place(const int* __restrict__ idx32, int* __restrict__ offs,
                        int* __restrict__ tokList) {
    int t = blockIdx.x * blockDim.x + threadIdx.x;
    if (t >= NTOK) return;
    int j = idx32[t];
    int p = atomicAdd(&offs[j], 1);
    tokList[p] = t;
}

// ---------------- fused: dw partials (latency-bound) || zq gather (write-BW-bound) ----------------
__global__ __launch_bounds__(512) void k_dwzq(const unsigned short* __restrict__ zh,
                       const int* __restrict__ cnt, const int* __restrict__ offs,
                       const int* __restrict__ tokList, float* __restrict__ dwp,
                       const float* __restrict__ emb, const int* __restrict__ idx32,
                       float* __restrict__ out_zq) {
    __shared__ float red[8][256];
    if (blockIdx.x < N_E) {
        const int j = blockIdx.x;
        const int split = blockIdx.y;          // 0..NSPL-1
        const int g = threadIdx.x >> 6;        // 0..7
        const int lane = threadIdx.x & 63;
        const int n = cnt[j];
        const int s0 = offs[j] - n;            // offs holds end positions after k_place
        const int stride = NSPL * 8;           // 32
        float4 acc = make_float4(0.f, 0.f, 0.f, 0.f);
        int i = split * 8 + g;
        if (i < n) {
            int t_cur = tokList[s0 + i];
            i += stride;
            for (; i < n; i += stride) {
                int t_nxt = tokList[s0 + i];   // overlaps with zh gather below
                ushort4 h = *(const ushort4*)&zh[(size_t)t_cur * 256 + lane * 4];
                acc.x += h2f(h.x); acc.y += h2f(h.y);
                acc.z += h2f(h.z); acc.w += h2f(h.w);
                t_cur = t_nxt;
            }
            ushort4 h = *(const ushort4*)&zh[(size_t)t_cur * 256 + lane * 4];
            acc.x += h2f(h.x); acc.y += h2f(h.y);
            acc.z += h2f(h.z); acc.w += h2f(h.w);
        }
        red[g][lane * 4 + 0] = acc.x; red[g][lane * 4 + 1] = acc.y;
        red[g][lane * 4 + 2] = acc.z; red[g][lane * 4 + 3] = acc.w;
        __syncthreads();
        if (g == 0) {
            float4 o;
            int c = lane * 4;
            o.x = red[0][c+0] + red[1][c+0] + red[2][c+0] + red[3][c+0]
                + red[4][c+0] + red[5][c+0] + red[6][c+0] + red[7][c+0];
            o.y = red[0][c+1] + red[1][c+1] + red[2][c+1] + red[3][c+1]
                + red[4][c+1] + red[5][c+1] + red[6][c+1] + red[7][c+1];
            o.z = red[0][c+2] + red[1][c+2] + red[2][c+2] + red[3][c+2]
                + red[4][c+2] + red[5][c+2] + red[6][c+2] + red[7][c+2];
            o.w = red[0][c+3] + red[1][c+3] + red[2][c+3] + red[3][c+3]
                + red[4][c+3] + red[5][c+3] + red[6][c+3] + red[7][c+3];
            ((float4*)dwp)[((size_t)split * N_E + j) * 64 + lane] = o;
        }
    } else {
        // zq role: 512 tokens per block, thread-per-token, 256B-contiguous wave stores
        int t = (blockIdx.x - N_E) * (NSPL * 512) + blockIdx.y * 512 + threadIdx.x;
        int j = idx32[t];
        int b = t >> 12, x = t & 4095;
        const float4* er = (const float4*)(emb + (size_t)j * E_DIM);
        float* ob = out_zq + (size_t)b * (E_DIM * ZX) + x;
        #pragma unroll 8
        for (int c4 = 0; c4 < E_DIM / 4; c4++) {
            float4 v = er[c4];
            ob[(size_t)(c4 * 4 + 0) * ZX] = v.x;
            ob[(size_t)(c4 * 4 + 1) * ZX] = v.y;
            ob[(size_t)(c4 * 4 + 2) * ZX] = v.z;
            ob[(size_t)(c4 * 4 + 3) * ZX] = v.w;
        }
    }
}

// ---------------- final: sum split partials + EMA epilogue ----------------
__global__ void k_final(const float* __restrict__ dwp, const int* __restrict__ cnt,
                        const float* __restrict__ cluster_size,
                        const float* __restrict__ emb_avg, const float* __restrict__ nval,
                        float* __restrict__ out_cluster, float* __restrict__ out_avg,
                        float* __restrict__ out_embed) {
    int j = blockIdx.x * 4 + (threadIdx.x >> 6);
    int lane = threadIdx.x & 63;
    float4 dw = make_float4(0.f, 0.f, 0.f, 0.f);
    #pragma unroll
    for (int s = 0; s < NSPL; ++s) {
        float4 v = ((const float4*)dwp)[((size_t)s * N_E + j) * 64 + lane];
        dw.x += v.x; dw.y += v.y; dw.z += v.z; dw.w += v.w;
    }
    float nc = cluster_size[j] * DECAY + (1.f - DECAY) * (float)cnt[j];
    float nv = *nval;
    float cs = (nc + EPSV) / (nv + (float)N_E * EPSV) * nv;
    float4 ea = ((const float4*)emb_avg)[(size_t)j * 64 + lane];
    float4 na, ne;
    na.x = ea.x * DECAY + (1.f - DECAY) * dw.x;
    na.y = ea.y * DECAY + (1.f - DECAY) * dw.y;
    na.z = ea.z * DECAY + (1.f - DECAY) * dw.z;
    na.w = ea.w * DECAY + (1.f - DECAY) * dw.w;
    ne.x = na.x / cs; ne.y = na.y / cs; ne.z = na.z / cs; ne.w = na.w / cs;
    ((float4*)out_avg)[(size_t)j * 64 + lane] = na;
    ((float4*)out_embed)[(size_t)j * 64 + lane] = ne;
    if (lane == 0) out_cluster[j] = nc;
}

extern "C" void kernel_launch(void* const* d_in, const int* in_sizes, int n_in,
                              void* d_out, int out_size, void* d_ws, size_t ws_size,
                              hipStream_t stream) {
    const float* z            = (const float*)d_in[0];
    const float* emb          = (const float*)d_in[1];
    const float* cluster_size = (const float*)d_in[2];
    const float* emb_avg      = (const float*)d_in[3];
    float* out = (float*)d_out;

    // ---- d_ws layout (bytes), ~35.8 MB (R1 used 39.6 MB safely) ----
    char* ws = (char*)d_ws;
    unsigned short* zh   = (unsigned short*)(ws + 0);          // 16,777,216 (f16)
    float* enorm32       = (float*)(ws + 16777216);            // 16,384
    double* enorm64      = (double*)(ws + 16793600);           // 32,768
    int* idx32           = (int*)(ws + 16826368);              // 131,072
    int* flagList        = (int*)(ws + 16957440);              // 131,072
    int* flagList2       = (int*)(ws + 17088512);              // 131,072
    int* xlist           = (int*)(ws + 17219584);              // 1,048,576
    int* xn              = (int*)(ws + 18268160);              // 131,072
    int* cnt             = (int*)(ws + 18399232);              // 16,384
    int* offs            = (int*)(ws + 18415616);              // 16,384
    int* flagCnt         = (int*)(ws + 18432000);              // 64
    int* flagCnt2        = (int*)(ws + 18432064);              // 64
    float* nval          = (float*)(ws + 18432128);            // 64
    float* dwp           = (float*)(ws + 18874368);            // 16,777,216 (NSPL partials)
    int*   tokList       = (int*)(ws + 35651584);              // 131,072 (ends 35,782,656)

    // ---- scratch inside d_out's zq region (pk/Bp dead before zq written) ----
    unsigned* pk1        = (unsigned*)(out + 0);        // 4 MB
    unsigned* pk2        = (unsigned*)(out + 1048576);  // 4 MB
    unsigned* pk3        = (unsigned*)(out + 2097152);  // 4 MB
    unsigned short* Bp   = (unsigned short*)(out + 3145728);   // 2 MB

    // ---- output sections ----
    float* out_zq      = out + 0;
    float* out_idx     = out + 8388608;
    float* out_cluster = out + 8421376;
    float* out_avg     = out + 8425472;
    float* out_embed   = out + 9474048;
    float* out_usage   = out + 10522624;

    hipLaunchKernelGGL(k_prep,   dim3(3072), dim3(256), 0, stream,
                       z, zh, emb, Bp, enorm32, enorm64, cnt, flagCnt, flagCnt2);
    hipLaunchKernelGGL(k_dist,   dim3(256, NJB), dim3(256), 0, stream,
                       zh, Bp, enorm32, pk1, pk2, pk3);
    hipLaunchKernelGGL(k_merge,  dim3(128), dim3(256), 0, stream,
                       pk1, pk2, pk3, idx32, cnt, out_idx,
                       xlist, xn, flagList, flagCnt, flagList2, flagCnt2);
    hipLaunchKernelGGL(k_triR,   dim3(512), dim3(512), 0, stream,
                       z, emb, enorm64, flagList, flagCnt, xlist, xn,
                       flagList2, flagCnt2, idx32, cnt, out_idx);
    hipLaunchKernelGGL(k_scan,   dim3(1), dim3(1024), 0, stream, cnt, offs,
                       cluster_size, nval, out_usage);
    hipLaunchKernelGGL(k_place,  dim3(128), dim3(256), 0, stream, idx32, offs, tokList);
    hipLaunchKernelGGL(k_dwzq,   dim3(N_E + 16, NSPL), dim3(512), 0, stream,
                       zh, cnt, offs, tokList, dwp, emb, idx32, out_zq);
    hipLaunchKernelGGL(k_final,  dim3(1024), dim3(256), 0, stream,
                       dwp, cnt, cluster_size, emb_avg, nval,
                       out_cluster, out_avg, out_embed);
}

// Round 18
// 197.680 us; speedup vs baseline: 1.1165x; 1.0159x over previous
//
#include <hip/hip_runtime.h>

#define N_E   4096
#define E_DIM 256
#define NTOK  32768
#define ZX    4096
#define DECAY 0.99f
#define EPSV  1e-5f
#define TAU   0.3f
#define NJB   32        // N_E / 128 j-blocks
#define NSPL  4         // dw splits per code
#define IBIG  0x7fffffff

typedef _Float16 half8 __attribute__((ext_vector_type(8)));
typedef __attribute__((ext_vector_type(4))) float f32x4;

__device__ __forceinline__ unsigned short f2h(float x) {
    _Float16 h = (_Float16)x;
    unsigned short u;
    __builtin_memcpy(&u, &h, 2);
    return u;
}
__device__ __forceinline__ float h2f(unsigned short u) {
    _Float16 h;
    __builtin_memcpy(&h, &u, 2);
    return (float)h;
}
__device__ __forceinline__ unsigned umin2(unsigned a, unsigned b) { return a < b ? a : b; }
__device__ __forceinline__ unsigned umax2(unsigned a, unsigned b) { return a > b ? a : b; }
__device__ __forceinline__ unsigned umed3(unsigned a, unsigned b, unsigned c) {
    unsigned d;
    asm("v_med3_u32 %0, %1, %2, %3" : "=v"(d) : "v"(a), "v"(b), "v"(c));
    return d;
}
__device__ __forceinline__ void gload16(const void* g, void* l) {
    __builtin_amdgcn_global_load_lds(
        (const __attribute__((address_space(1))) char*)g,
        (__attribute__((address_space(3))) char*)l, 16, 0, 0);
}

// ---------------- fused prep: blocks <2048 do z->f16; rest do emb prep + init ----------------
__global__ void k_prep(const float* __restrict__ z, unsigned short* __restrict__ zh,
                       const float* __restrict__ emb, unsigned short* __restrict__ Bp,
                       float* __restrict__ enorm32, double* __restrict__ enorm64,
                       int* __restrict__ cnt, int* __restrict__ flagCnt,
                       int* __restrict__ flagCnt2) {
    __shared__ float lt[64][65];
    const int tid = threadIdx.x;
    if (blockIdx.x < 2048) {
        const int bid = blockIdx.x;
        const int xt = bid & 63, ct = (bid >> 6) & 3, b = bid >> 8;
        #pragma unroll
        for (int r = 0; r < 4; ++r) {
            int cy = r * 16 + (tid >> 4);
            int xx4 = tid & 15;
            float4 v = ((const float4*)z)[(size_t)(b * 256 + ct * 64 + cy) * 1024 + xt * 16 + xx4];
            lt[cy][xx4 * 4 + 0] = v.x; lt[cy][xx4 * 4 + 1] = v.y;
            lt[cy][xx4 * 4 + 2] = v.z; lt[cy][xx4 * 4 + 3] = v.w;
        }
        __syncthreads();
        #pragma unroll
        for (int it = 0; it < 2; ++it) {
            int tl = it * 32 + (tid >> 3);
            int c8 = tid & 7;
            unsigned short h[8];
            #pragma unroll
            for (int u = 0; u < 8; ++u) h[u] = f2h(lt[c8 * 8 + u][tl]);
            size_t t = (size_t)(b * 4096 + xt * 64 + tl);
            size_t o = t * 256 + ct * 64 + c8 * 8;
            *(ushort4*)&zh[o]     = make_ushort4(h[0], h[1], h[2], h[3]);
            *(ushort4*)&zh[o + 4] = make_ushort4(h[4], h[5], h[6], h[7]);
        }
    } else {
        const int eb = blockIdx.x - 2048;
        if (tid < 4) cnt[eb * 4 + tid] = 0;
        if (eb == 0 && tid == 0) { *flagCnt = 0; *flagCnt2 = 0; }
        int j = eb * 4 + (tid >> 6);
        int lane = tid & 63;
        float4 v = ((const float4*)emb)[(size_t)j * 64 + lane];
        float f[4] = {v.x, v.y, v.z, v.w};
        unsigned short h[4];
        #pragma unroll
        for (int u = 0; u < 4; ++u) h[u] = f2h(f[u]);
        *(ushort4*)&Bp[(size_t)j * E_DIM + lane * 4] = make_ushort4(h[0], h[1], h[2], h[3]);
        double s = 0.0;
        #pragma unroll
        for (int u = 0; u < 4; ++u) s += (double)f[u] * (double)f[u];
        #pragma unroll
        for (int off = 32; off; off >>= 1) s += __shfl_down(s, off, 64);
        if (lane == 0) { enorm32[j] = (float)s; enorm64[j] = s; }
    }
}

// ---------------- MFMA f16 distance; XCD-slab swizzle; per-jb top-3 packed keys ----------------
__global__ __launch_bounds__(256) void k_dist(
        const unsigned short* __restrict__ zh,
        const unsigned short* __restrict__ Bp, const float* __restrict__ enorm32,
        unsigned* __restrict__ pk1, unsigned* __restrict__ pk2, unsigned* __restrict__ pk3) {
    __shared__ __align__(16) char smem[32768];   // single buffer: 16KB A + 16KB B
    const int tid = threadIdx.x;
    const int lane = tid & 63;
    const int w = tid >> 6;
    const int wr = w >> 1, wc = w & 1;
    // XCD slab swizzle: xcd = n&7 owns tb-slab [xcd*32, xcd*32+32)
    const int n = blockIdx.y * 256 + blockIdx.x;
    const int xcd = n & 7;
    const int mq = n >> 3;
    const int tb = xcd * 32 + (mq & 31);
    const int jb = mq >> 5;
    const int t0 = tb * 128;
    const int j0 = jb * 128;
    const int sw16 = (((lane & 7) ^ (lane >> 3)) << 4);
    const int rowsub = lane >> 3;

    f32x4 acc[4][4];
    #pragma unroll
    for (int m = 0; m < 4; ++m)
        #pragma unroll
        for (int nn = 0; nn < 4; ++nn)
            acc[m][nn] = (f32x4){0.f, 0.f, 0.f, 0.f};

    // hoisted per-wave staging base pointers (8 total, stage offset = s*128 imm)
    const char* aB[4]; const char* bB[4];
    #pragma unroll
    for (int c = 0; c < 4; ++c) {
        int seg = w * 4 + c;
        aB[c] = (const char*)zh + (size_t)(t0 + seg * 8 + rowsub) * 512 + sw16;
        bB[c] = (const char*)Bp + (size_t)(j0 + seg * 8 + rowsub) * 512 + sw16;
    }
    auto stage = [&](int s) {
        const int kb = s * 128;
        #pragma unroll
        for (int c = 0; c < 4; ++c) {
            gload16(aB[c] + kb, &smem[(w * 4 + c) * 1024]);
            gload16(bB[c] + kb, &smem[16384 + (w * 4 + c) * 1024]);
        }
    };

    stage(0);
    #pragma unroll
    for (int s = 0; s < 4; ++s) {
        __syncthreads();                 // staged data visible (vmcnt drained)
        const int xr = ((lane & 7) << 4);
        #pragma unroll
        for (int kk = 0; kk < 2; ++kk) {
            const int colb = (kk * 64 + ((lane >> 4) << 4)) ^ xr;
            half8 a[4], b[4];
            #pragma unroll
            for (int m = 0; m < 4; ++m)
                a[m] = *(const half8*)&smem[((wr * 64 + m * 16 + (lane & 15)) << 7) + colb];
            #pragma unroll
            for (int nn = 0; nn < 4; ++nn)
                b[nn] = *(const half8*)&smem[16384 + ((wc * 64 + nn * 16 + (lane & 15)) << 7) + colb];
            // swapped operands: D[row=code, col=token]
            #pragma unroll
            for (int m = 0; m < 4; ++m)
                #pragma unroll
                for (int nn = 0; nn < 4; ++nn)
                    acc[m][nn] = __builtin_amdgcn_mfma_f32_16x16x32_f16(b[nn], a[m], acc[m][nn], 0, 0, 0);
        }
        if (s < 3) {
            __syncthreads();             // all waves done reading -> safe to overwrite
            stage(s + 1);
        }
    }

    // ---- epilogue: per-(wc)half top-3 packed u32 keys (7-bit code); med3 inserts ----
    const int g   = lane >> 4;       // code row-group
    const int gg4 = g * 4;
    const int cbase = (wc << 6);
    float enb[4][4];
    #pragma unroll
    for (int nn = 0; nn < 4; ++nn) {
        float4 e4 = *(const float4*)&enorm32[j0 + wc * 64 + nn * 16 + gg4];
        enb[nn][0] = e4.x + 4096.f; enb[nn][1] = e4.y + 4096.f;
        enb[nn][2] = e4.z + 4096.f; enb[nn][3] = e4.w + 4096.f;
    }
    unsigned s1 = 0, s2 = 0, s3 = 0;
    #pragma unroll
    for (int m = 0; m < 4; ++m) {
        unsigned k1 = 0xFFFFFFFFu, k2 = 0xFFFFFFFFu, k3 = 0xFFFFFFFFu;
        #pragma unroll
        for (int nn = 0; nn < 4; ++nn)
            #pragma unroll
            for (int r = 0; r < 4; ++r) {
                float sc = fmaf(-2.f, acc[m][nn][r], enb[nn][r]);   // > 0 by construction
                unsigned key = (__float_as_uint(sc) & 0xFFFFFF80u)
                             | (unsigned)(cbase | (gg4 + nn * 16 + r));
                // sorted-triple insert via med3 (k1<=k2<=k3 invariant)
                k3 = umed3(k2, k3, key);
                k2 = umed3(k1, k2, key);
                k1 = umin2(k1, key);
            }
        #pragma unroll
        for (int off = 16; off <= 32; off <<= 1) {
            unsigned b1 = (unsigned)__shfl_xor((int)k1, off, 64);
            unsigned b2 = (unsigned)__shfl_xor((int)k2, off, 64);
            unsigned b3 = (unsigned)__shfl_xor((int)k3, off, 64);
            // merge two sorted triples (med3 form)
            unsigned x  = umin2(k2, b2);
            unsigned p  = umax2(k1, b1);
            unsigned r2 = umax2(k2, b2);
            unsigned ss = umin2(k3, b3);
            unsigned u  = umin2(r2, ss);
            unsigned m1 = umin2(k1, b1);
            unsigned m2 = umed3(k1, b1, x);
            unsigned m3 = umed3(x, p, u);
            k1 = m1; k2 = m2; k3 = m3;
        }
        s1 = (g == m) ? k1 : s1;
        s2 = (g == m) ? k2 : s2;
        s3 = (g == m) ? k3 : s3;
    }
    // ---- cross-wc merge via LDS (tiles dead after barrier) -> per-128-code top-3 ----
    unsigned* mb = (unsigned*)smem;      // [3][2][64]
    __syncthreads();                     // all GEMM LDS reads complete
    if (wc == 1) {
        mb[wr * 64 + lane]       = s1;
        mb[128 + wr * 64 + lane] = s2;
        mb[256 + wr * 64 + lane] = s3;
    }
    __syncthreads();
    if (wc == 0) {
        unsigned o1 = mb[wr * 64 + lane];
        unsigned o2 = mb[128 + wr * 64 + lane];
        unsigned o3 = mb[256 + wr * 64 + lane];
        unsigned x  = umin2(s2, o2);
        unsigned p  = umax2(s1, o1);
        unsigned C  = umax2(s2, o2);
        unsigned D  = umin2(s3, o3);
        unsigned u  = umin2(C, D);
        unsigned r1 = umin2(s1, o1);
        unsigned r2 = umed3(s1, o1, x);
        unsigned r3 = umed3(x, p, u);
        size_t o = (size_t)jb * NTOK + t0 + wr * 64 + lane;
        pk1[o] = r1; pk2[o] = r2; pk3[o] = r3;
    }
}

// ---------------- merge jb-blocks on keys, histogram, candidate collection ----------------
__global__ void k_merge(const unsigned* __restrict__ pk1, const unsigned* __restrict__ pk2,
                        const unsigned* __restrict__ pk3,
                        int* __restrict__ idx32, int* __restrict__ cnt,
                        float* __restrict__ out_idx,
                        int* __restrict__ xlist, int* __restrict__ xn,
                        int* __restrict__ flagList, int* __restrict__ flagCount,
                        int* __restrict__ flagList2, int* __restrict__ flagCount2) {
    int t = blockIdx.x * blockDim.x + threadIdx.x;
    if (t >= NTOK) return;
    unsigned g1 = 0xFFFFFFFFu, g2 = 0xFFFFFFFFu;
    int h1 = 0;
    #pragma unroll 4
    for (int s = 0; s < NJB; s++) {
        unsigned a = pk1[(size_t)s * NTOK + t];
        unsigned b = pk2[(size_t)s * NTOK + t];
        bool c = a < g1;
        g2 = c ? g1 : umin2(g2, a);
        h1 = c ? s : h1;
        g1 = c ? a : g1;
        g2 = umin2(g2, b);          // b >= a so never the global min
    }
    int x1 = h1 * 128 + (int)(g1 & 127u);
    idx32[t] = x1;
    atomicAdd(&cnt[x1], 1);
    out_idx[t] = (float)x1;
    float v1 = __uint_as_float(g1 & 0xFFFFFF80u);
    float v2 = __uint_as_float(g2 & 0xFFFFFF80u);
    if (v2 - v1 >= TAU) return;     // winner certain at fp16 precision
    unsigned thrk = __float_as_uint(v1 + TAU) | 127u;
    int nc = 0; bool full = false;
    for (int s = 0; s < NJB; s++) {
        unsigned a = pk1[(size_t)s * NTOK + t];
        if (a > thrk) continue;
        if (pk3[(size_t)s * NTOK + t] <= thrk) { full = true; break; }  // >=3 in band
        if (nc == 8) { full = true; break; }
        xlist[t * 8 + nc++] = s * 128 + (int)(a & 127u);
        unsigned b = pk2[(size_t)s * NTOK + t];
        if (b <= thrk) {
            if (nc == 8) { full = true; break; }
            xlist[t * 8 + nc++] = s * 128 + (int)(b & 127u);
        }
    }
    if (full) {
        int q = atomicAdd(flagCount2, 1);
        flagList2[q] = t;
    } else {
        xn[t] = nc;
        int q = atomicAdd(flagCount, 1);
        flagList[q] = t;
    }
}

// ---------------- fused referee: blocks<384 tri (candidate lists), rest full recheck ----------------
__global__ __launch_bounds__(512) void k_triR(
        const float* __restrict__ z, const float* __restrict__ emb,
        const double* __restrict__ enorm64,
        const int* __restrict__ flagList, const int* __restrict__ flagCount,
        const int* __restrict__ xlist, const int* __restrict__ xn,
        const int* __restrict__ flagList2, const int* __restrict__ flagCount2,
        int* __restrict__ idx32, int* __restrict__ cnt, float* __restrict__ out_idx) {
    __shared__ float zrow[E_DIM];
    __shared__ double rv[512];
    __shared__ int ri[512];
    const int tid = threadIdx.x;
    if (blockIdx.x < 384) {
        // ---- tri role: exact fp64 over <=8 candidates, one wave per token ----
        const int lane = tid & 63;
        const int wid = blockIdx.x * 8 + (tid >> 6);
        const int nw = 384 * 8;
        const int nf = *flagCount;
        for (int f = wid; f < nf; f += nw) {
            int t = flagList[f];
            int b = t >> 12, x = t & 4095;
            double zz[4];
            #pragma unroll
            for (int u = 0; u < 4; ++u)
                zz[u] = (double)z[(size_t)(b * 256 + lane * 4 + u) * 4096 + x];
            int m = xn[t];
            double best = 1e300; int bi = IBIG;
            for (int c = 0; c < m; ++c) {
                int j = xlist[t * 8 + c];
                float4 e = ((const float4*)emb)[(size_t)j * 64 + lane];
                double d = zz[0] * (double)e.x + zz[1] * (double)e.y
                         + zz[2] * (double)e.z + zz[3] * (double)e.w;
                #pragma unroll
                for (int off = 32; off; off >>= 1) d += __shfl_down(d, off, 64);
                double s = enorm64[j] - 2.0 * d;   // valid on lane 0
                if (s < best || (s == best && j < bi)) { best = s; bi = j; }
            }
            if (lane == 0) {
                int old = idx32[t];
                if (bi != old) {
                    idx32[t] = bi;
                    out_idx[t] = (float)bi;
                    atomicSub(&cnt[old], 1);
                    atomicAdd(&cnt[bi], 1);
                }
            }
        }
    } else {
        // ---- recheck role: full fp64 row scan ----
        const int nf = *flagCount2;
        for (int f = blockIdx.x - 384; f < nf; f += 128) {
            const int t = flagList2[f];
            const int b = t >> 12, x = t & 4095;
            __syncthreads();
            if (tid < E_DIM) zrow[tid] = z[(size_t)(b * 256 + tid) * 4096 + x];
            __syncthreads();
            double best = 1e300; int bi = IBIG;
            for (int s = 0; s < N_E / 512; s++) {
                int j = s * 512 + tid;
                const float4* er4 = (const float4*)(emb + (size_t)j * E_DIM);
                double a0 = 0.0, a1 = 0.0, a2 = 0.0, a3 = 0.0;
                for (int k4 = 0; k4 < 64; ++k4) {
                    float4 e = er4[k4];
                    a0 = fma((double)e.x, (double)zrow[k4 * 4 + 0], a0);
                    a1 = fma((double)e.y, (double)zrow[k4 * 4 + 1], a1);
                    a2 = fma((double)e.z, (double)zrow[k4 * 4 + 2], a2);
                    a3 = fma((double)e.w, (double)zrow[k4 * 4 + 3], a3);
                }
                double d = enorm64[j] - 2.0 * ((a0 + a1) + (a2 + a3));
                if (d < best || (d == best && j < bi)) { best = d; bi = j; }
            }
            rv[tid] = best; ri[tid] = bi;
            __syncthreads();
            for (int off = 256; off; off >>= 1) {
                if (tid < off) {
                    if (rv[tid + off] < rv[tid] ||
                        (rv[tid + off] == rv[tid] && ri[tid + off] < ri[tid])) {
                        rv[tid] = rv[tid + off]; ri[tid] = ri[tid + off];
                    }
                }
                __syncthreads();
            }
            if (tid == 0) {
                int old = idx32[t];
                int nw2 = ri[0];
                if (nw2 != old) {
                    idx32[t] = nw2;
                    out_idx[t] = (float)nw2;
                    atomicSub(&cnt[old], 1);
                    atomicAdd(&cnt[nw2], 1);
                }
            }
            __syncthreads();
        }
    }
}

// ---------------- exclusive scan of cnt[4096] + n/usage stats ----------------
__global__ void k_scan(const int* __restrict__ cnt, int* __restrict__ offs,
                       const float* __restrict__ cluster_size,
                       float* __restrict__ nval, float* __restrict__ out_usage) {
    __shared__ int sc[1024];
    __shared__ float sn[1024];
    __shared__ float su[1024];
    int tid = threadIdx.x;
    int c0 = cnt[tid * 4], c1 = cnt[tid * 4 + 1], c2 = cnt[tid * 4 + 2], c3 = cnt[tid * 4 + 3];
    int ls = c0 + c1 + c2 + c3;
    float ns = 0.f, us = 0.f;
    {
        int cc[4] = {c0, c1, c2, c3};
        #pragma unroll
        for (int u = 0; u < 4; ++u) {
            ns += cluster_size[tid * 4 + u] * DECAY + (1.f - DECAY) * (float)cc[u];
            us += (cc[u] > 0) ? 1.f : 0.f;
        }
    }
    sc[tid] = ls; sn[tid] = ns; su[tid] = us;
    __syncthreads();
    for (int off = 1; off < 1024; off <<= 1) {
        int v = (tid >= off) ? sc[tid - off] : 0;
        __syncthreads();
        sc[tid] += v;
        __syncthreads();
    }
    int base = sc[tid] - ls;
    offs[tid * 4] = base;
    offs[tid * 4 + 1] = base + c0;
    offs[tid * 4 + 2] = base + c0 + c1;
    offs[tid * 4 + 3] = base + c0 + c1 + c2;
    for (int off = 512; off; off >>= 1) {
        if (tid < off) { sn[tid] += sn[tid + off]; su[tid] += su[tid + off]; }
        __syncthreads();
    }
    if (tid == 0) { *nval = sn[0]; *out_usage = su[0] / (float)N_E; }
}

// ---------------- place tokens into per-code lists ----------------
__global__ void k_place(const int* __restrict__ idx32, int* __restrict__ offs,
                        int* __restrict__ tokList) {
    int t = blockIdx.x * blockDim.x + threadIdx.x;
    if (t >= NTOK) return;
    int j = idx32[t];
    int p = atomicAdd(&offs[j], 1);
    tokList[p] = t;
}

// ---------------- fused: dw partials (latency-bound) || zq gather (write-BW-bound) ----------------
__global__ __launch_bounds__(512) void k_dwzq(const unsigned short* __restrict__ zh,
                       const int* __restrict__ cnt, const int* __restrict__ offs,
                       const int* __restrict__ tokList, float* __restrict__ dwp,
                       const float* __restrict__ emb, const int* __restrict__ idx32,
                       float* __restrict__ out_zq) {
    __shared__ float red[8][256];
    if (blockIdx.x < N_E) {
        const int j = blockIdx.x;
        const int split = blockIdx.y;          // 0..NSPL-1
        const int g = threadIdx.x >> 6;        // 0..7
        const int lane = threadIdx.x & 63;
        const int n = cnt[j];
        const int s0 = offs[j] - n;            // offs holds end positions after k_place
        const int stride = NSPL * 8;           // 32
        float4 acc = make_float4(0.f, 0.f, 0.f, 0.f);
        int i = split * 8 + g;
        if (i < n) {
            int t_cur = tokList[s0 + i];
            i += stride;
            for (; i < n; i += stride) {
                int t_nxt = tokList[s0 + i];   // overlaps with zh gather below
                ushort4 h = *(const ushort4*)&zh[(size_t)t_cur * 256 + lane * 4];
                acc.x += h2f(h.x); acc.y += h2f(h.y);
                acc.z += h2f(h.z); acc.w += h2f(h.w);
                t_cur = t_nxt;
            }
            ushort4 h = *(const ushort4*)&zh[(size_t)t_cur * 256 + lane * 4];
            acc.x += h2f(h.x); acc.y += h2f(h.y);
            acc.z += h2f(h.z); acc.w += h2f(h.w);
        }
        red[g][lane * 4 + 0] = acc.x; red[g][lane * 4 + 1] = acc.y;
        red[g][lane * 4 + 2] = acc.z; red[g][lane * 4 + 3] = acc.w;
        __syncthreads();
        if (g == 0) {
            float4 o;
            int c = lane * 4;
            o.x = red[0][c+0] + red[1][c+0] + red[2][c+0] + red[3][c+0]
                + red[4][c+0] + red[5][c+0] + red[6][c+0] + red[7][c+0];
            o.y = red[0][c+1] + red[1][c+1] + red[2][c+1] + red[3][c+1]
                + red[4][c+1] + red[5][c+1] + red[6][c+1] + red[7][c+1];
            o.z = red[0][c+2] + red[1][c+2] + red[2][c+2] + red[3][c+2]
                + red[4][c+2] + red[5][c+2] + red[6][c+2] + red[7][c+2];
            o.w = red[0][c+3] + red[1][c+3] + red[2][c+3] + red[3][c+3]
                + red[4][c+3] + red[5][c+3] + red[6][c+3] + red[7][c+3];
            ((float4*)dwp)[((size_t)split * N_E + j) * 64 + lane] = o;
        }
    } else {
        // zq role: 512 tokens per block, thread-per-token, 256B-contiguous wave stores
        int t = (blockIdx.x - N_E) * (NSPL * 512) + blockIdx.y * 512 + threadIdx.x;
        int j = idx32[t];
        int b = t >> 12, x = t & 4095;
        const float4* er = (const float4*)(emb + (size_t)j * E_DIM);
        float* ob = out_zq + (size_t)b * (E_DIM * ZX) + x;
        #pragma unroll 8
        for (int c4 = 0; c4 < E_DIM / 4; c4++) {
            float4 v = er[c4];
            ob[(size_t)(c4 * 4 + 0) * ZX] = v.x;
            ob[(size_t)(c4 * 4 + 1) * ZX] = v.y;
            ob[(size_t)(c4 * 4 + 2) * ZX] = v.z;
            ob[(size_t)(c4 * 4 + 3) * ZX] = v.w;
        }
    }
}

// ---------------- final: sum split partials + EMA epilogue ----------------
__global__ void k_final(const float* __restrict__ dwp, const int* __restrict__ cnt,
                        const float* __restrict__ cluster_size,
                        const float* __restrict__ emb_avg, const float* __restrict__ nval,
                        float* __restrict__ out_cluster, float* __restrict__ out_avg,
                        float* __restrict__ out_embed) {
    int j = blockIdx.x * 4 + (threadIdx.x >> 6);
    int lane = threadIdx.x & 63;
    float4 dw = make_float4(0.f, 0.f, 0.f, 0.f);
    #pragma unroll
    for (int s = 0; s < NSPL; ++s) {
        float4 v = ((const float4*)dwp)[((size_t)s * N_E + j) * 64 + lane];
        dw.x += v.x; dw.y += v.y; dw.z += v.z; dw.w += v.w;
    }
    float nc = cluster_size[j] * DECAY + (1.f - DECAY) * (float)cnt[j];
    float nv = *nval;
    float cs = (nc + EPSV) / (nv + (float)N_E * EPSV) * nv;
    float4 ea = ((const float4*)emb_avg)[(size_t)j * 64 + lane];
    float4 na, ne;
    na.x = ea.x * DECAY + (1.f - DECAY) * dw.x;
    na.y = ea.y * DECAY + (1.f - DECAY) * dw.y;
    na.z = ea.z * DECAY + (1.f - DECAY) * dw.z;
    na.w = ea.w * DECAY + (1.f - DECAY) * dw.w;
    ne.x = na.x / cs; ne.y = na.y / cs; ne.z = na.z / cs; ne.w = na.w / cs;
    ((float4*)out_avg)[(size_t)j * 64 + lane] = na;
    ((float4*)out_embed)[(size_t)j * 64 + lane] = ne;
    if (lane == 0) out_cluster[j] = nc;
}

extern "C" void kernel_launch(void* const* d_in, const int* in_sizes, int n_in,
                              void* d_out, int out_size, void* d_ws, size_t ws_size,
                              hipStream_t stream) {
    const float* z            = (const float*)d_in[0];
    const float* emb          = (const float*)d_in[1];
    const float* cluster_size = (const float*)d_in[2];
    const float* emb_avg      = (const float*)d_in[3];
    float* out = (float*)d_out;

    // ---- d_ws layout (bytes), ~35.8 MB (R1 used 39.6 MB safely) ----
    char* ws = (char*)d_ws;
    unsigned short* zh   = (unsigned short*)(ws + 0);          // 16,777,216 (f16)
    float* enorm32       = (float*)(ws + 16777216);            // 16,384
    double* enorm64      = (double*)(ws + 16793600);           // 32,768
    int* idx32           = (int*)(ws + 16826368);              // 131,072
    int* flagList        = (int*)(ws + 16957440);              // 131,072
    int* flagList2       = (int*)(ws + 17088512);              // 131,072
    int* xlist           = (int*)(ws + 17219584);              // 1,048,576
    int* xn              = (int*)(ws + 18268160);              // 131,072
    int* cnt             = (int*)(ws + 18399232);              // 16,384
    int* offs            = (int*)(ws + 18415616);              // 16,384
    int* flagCnt         = (int*)(ws + 18432000);              // 64
    int* flagCnt2        = (int*)(ws + 18432064);              // 64
    float* nval          = (float*)(ws + 18432128);            // 64
    float* dwp           = (float*)(ws + 18874368);            // 16,777,216 (NSPL partials)
    int*   tokList       = (int*)(ws + 35651584);              // 131,072 (ends 35,782,656)

    // ---- scratch inside d_out's zq region (pk/Bp dead before zq written) ----
    unsigned* pk1        = (unsigned*)(out + 0);        // 4 MB
    unsigned* pk2        = (unsigned*)(out + 1048576);  // 4 MB
    unsigned* pk3        = (unsigned*)(out + 2097152);  // 4 MB
    unsigned short* Bp   = (unsigned short*)(out + 3145728);   // 2 MB

    // ---- output sections ----
    float* out_zq      = out + 0;
    float* out_idx     = out + 8388608;
    float* out_cluster = out + 8421376;
    float* out_avg     = out + 8425472;
    float* out_embed   = out + 9474048;
    float* out_usage   = out + 10522624;

    hipLaunchKernelGGL(k_prep,   dim3(3072), dim3(256), 0, stream,
                       z, zh, emb, Bp, enorm32, enorm64, cnt, flagCnt, flagCnt2);
    hipLaunchKernelGGL(k_dist,   dim3(256, NJB), dim3(256), 0, stream,
                       zh, Bp, enorm32, pk1, pk2, pk3);
    hipLaunchKernelGGL(k_merge,  dim3(128), dim3(256), 0, stream,
                       pk1, pk2, pk3, idx32, cnt, out_idx,
                       xlist, xn, flagList, flagCnt, flagList2, flagCnt2);
    hipLaunchKernelGGL(k_triR,   dim3(512), dim3(512), 0, stream,
                       z, emb, enorm64, flagList, flagCnt, xlist, xn,
                       flagList2, flagCnt2, idx32, cnt, out_idx);
    hipLaunchKernelGGL(k_scan,   dim3(1), dim3(1024), 0, stream, cnt, offs,
                       cluster_size, nval, out_usage);
    hipLaunchKernelGGL(k_place,  dim3(128), dim3(256), 0, stream, idx32, offs, tokList);
    hipLaunchKernelGGL(k_dwzq,   dim3(N_E + 16, NSPL), dim3(512), 0, stream,
                       zh, cnt, offs, tokList, dwp, emb, idx32, out_zq);
    hipLaunchKernelGGL(k_final,  dim3(1024), dim3(256), 0, stream,
                       dwp, cnt, cluster_size, emb_avg, nval,
                       out_cluster, out_avg, out_embed);
}